// Round 1
// baseline (426.185 us; speedup 1.0000x reference)
//
#include <hip/hip_runtime.h>

// TGNN encoder, fused single kernel: one block per batch row.
// B=1024, N=200, DN=DT=128, M=384.
// d_out layout: [ out (1024*128 f32) | attn_w (1024*200 f32) ]

constexpr int B_  = 1024;
constexpr int N_  = 200;
constexpr int DN_ = 128;
constexpr int DT_ = 128;
constexpr int M_  = 384;     // DN + DN + DT
constexpr int BDIM = 256;    // 4 waves
constexpr int NPW  = N_ / 4; // 50 keys per wave

__device__ __forceinline__ float wave_sum(float v) {
#pragma unroll
    for (int off = 32; off > 0; off >>= 1)
        v += __shfl_xor(v, off, 64);
    return v;
}

__global__ __launch_bounds__(BDIM) void tgnn_kernel(
    const float* __restrict__ src,      // (B, DN)
    const float* __restrict__ src_t,    // (B, 1, DT)
    const float* __restrict__ seq,      // (B, N, DN)
    const float* __restrict__ seq_t,    // (B, N, DT)
    const float* __restrict__ seq_e,    // (B, N, DN)
    const int*   __restrict__ mask,     // (B, N) int32 (bool)
    const float* __restrict__ shared_attn, // (2M,)
    const float* __restrict__ fc_w,     // (M, M)
    const float* __restrict__ ln_g,     // (M,)
    const float* __restrict__ ln_b,     // (M,)
    const float* __restrict__ w1,       // (2DN, M+DN) = (256, 512)
    const float* __restrict__ w2,       // (DN, 2DN)   = (128, 256)
    float* __restrict__ out,            // (B, DN)
    float* __restrict__ attn_out)       // (B, N)
{
    const int b    = blockIdx.x;
    const int tid  = threadIdx.x;
    const int wave = tid >> 6;
    const int lane = tid & 63;
    const int e0   = 2 * lane;      // this lane's element pair within a 128-slice
    const int e1   = e0 + 1;

    __shared__ float s_p[N_];          // unnormalized exp(score)
    __shared__ float s_q[M_];          // q = [src, 0, src_t]
    __shared__ float s_oa[4][M_];      // per-wave attention accumulators
    __shared__ float s_outattn[M_];    // attn @ k
    __shared__ float s_y[M_ + DN_];    // LN output, then concat src -> x[512]
    __shared__ float s_h[2 * DN_];     // relu(x @ w1.T)
    __shared__ float s_red[8];

    // ---- stage q into LDS ----
    if (tid < 128) {
        s_q[tid]       = src[b * DN_ + tid];
        s_q[128 + tid] = 0.0f;
        s_q[256 + tid] = src_t[b * DT_ + tid];
    }

    // ---- per-lane wk fragment (elements e0,e1 of each 128-slice) ----
    const float* wq = shared_attn;        // [0, M)
    const float* wk = shared_attn + M_;   // [M, 2M)
    const float wk0 = wk[e0],       wk1 = wk[e1];
    const float wk2 = wk[128 + e0], wk3 = wk[128 + e1];
    const float wk4 = wk[256 + e0], wk5 = wk[256 + e1];

    // ---- q-side score (constant over n), computed redundantly per wave ----
    float qpart = src[b * DN_ + e0] * wq[e0]
                + src[b * DN_ + e1] * wq[e1]
                + src_t[b * DT_ + e0] * wq[256 + e0]
                + src_t[b * DT_ + e1] * wq[256 + e1];
    const float qdot = wave_sum(qpart);

    // ---- fused score + online weighted-sum pass over this wave's keys ----
    float o0 = 0.f, o1 = 0.f, o2 = 0.f, o3 = 0.f, o4 = 0.f, o5 = 0.f;
    float lsum = 0.f;
    const int n_base = wave * NPW;
    for (int n = n_base; n < n_base + NPW; ++n) {
        const long row = (long)(b * N_ + n);
        const float2 a = *(const float2*)&seq  [row * DN_ + e0];
        const float2 e = *(const float2*)&seq_e[row * DN_ + e0];
        const float2 t = *(const float2*)&seq_t[row * DT_ + e0];
        float part = a.x * wk0 + a.y * wk1
                   + e.x * wk2 + e.y * wk3
                   + t.x * wk4 + t.y * wk5;
        float s = wave_sum(part) + qdot;
        float p = mask[row] ? 0.0f : __expf(s);  // masked -> exp(-1e10) == 0
        if (lane == 0) s_p[n] = p;
        lsum += p;
        o0 += p * a.x; o1 += p * a.y;
        o2 += p * e.x; o3 += p * e.y;
        o4 += p * t.x; o5 += p * t.y;
    }

    // ---- combine 4 waves ----
    if (lane == 0) s_red[wave] = lsum;
    s_oa[wave][e0]       = o0; s_oa[wave][e1]       = o1;
    s_oa[wave][128 + e0] = o2; s_oa[wave][128 + e1] = o3;
    s_oa[wave][256 + e0] = o4; s_oa[wave][256 + e1] = o5;
    __syncthreads();

    const float Z    = s_red[0] + s_red[1] + s_red[2] + s_red[3];
    const float invZ = 1.0f / Z;

    for (int j = tid; j < M_; j += BDIM)
        s_outattn[j] = (s_oa[0][j] + s_oa[1][j] + s_oa[2][j] + s_oa[3][j]) * invZ;
    for (int n = tid; n < N_; n += BDIM)
        attn_out[b * N_ + n] = s_p[n] * invZ;
    __syncthreads();

    // ---- fc: out2[i] = dot(out_attn, fc_w[i,:]) + q[i]  (wave-cooperative) ----
    for (int r = 0; r < M_ / 4; ++r) {          // 96 outputs per wave
        const int i = wave * (M_ / 4) + r;
        const float* row = &fc_w[i * M_];
        float part = 0.f;
#pragma unroll
        for (int m = 0; m < 6; ++m)
            part += s_outattn[lane + 64 * m] * row[lane + 64 * m];
        float v = wave_sum(part);
        if (lane == 0) s_y[i] = v + s_q[i];
    }
    __syncthreads();

    // ---- layer norm over M ----
    float ls = 0.f, lq = 0.f;
    for (int j = tid; j < M_; j += BDIM) {
        float v = s_y[j];
        ls += v; lq += v * v;
    }
    ls = wave_sum(ls); lq = wave_sum(lq);
    if (lane == 0) { s_red[wave] = ls; s_red[4 + wave] = lq; }
    __syncthreads();
    const float mean = (s_red[0] + s_red[1] + s_red[2] + s_red[3]) * (1.0f / M_);
    const float msq  = (s_red[4] + s_red[5] + s_red[6] + s_red[7]) * (1.0f / M_);
    const float rstd = rsqrtf(msq - mean * mean + 1e-5f);
    for (int j = tid; j < M_; j += BDIM)
        s_y[j] = (s_y[j] - mean) * rstd * ln_g[j] + ln_b[j];
    if (tid < 128)
        s_y[M_ + tid] = s_q[tid];               // concat src
    __syncthreads();

    // ---- agg fc1: h[i] = relu(dot(x[512], w1[i,:])), i < 256 ----
    for (int r = 0; r < 64; ++r) {
        const int i = wave * 64 + r;
        const float* row = &w1[i * (M_ + DN_)];
        float part = 0.f;
#pragma unroll
        for (int m = 0; m < 8; ++m)
            part += s_y[lane + 64 * m] * row[lane + 64 * m];
        float v = wave_sum(part);
        if (lane == 0) s_h[i] = fmaxf(v, 0.0f);
    }
    __syncthreads();

    // ---- agg fc2: out[i] = dot(h[256], w2[i,:]), i < 128 ----
    for (int r = 0; r < 32; ++r) {
        const int i = wave * 32 + r;
        const float* row = &w2[i * (2 * DN_)];
        float part = 0.f;
#pragma unroll
        for (int m = 0; m < 4; ++m)
            part += s_h[lane + 64 * m] * row[lane + 64 * m];
        float v = wave_sum(part);
        if (lane == 0) out[b * DN_ + i] = v;
    }
}

extern "C" void kernel_launch(void* const* d_in, const int* in_sizes, int n_in,
                              void* d_out, int out_size, void* d_ws, size_t ws_size,
                              hipStream_t stream) {
    const float* src         = (const float*)d_in[0];
    const float* src_t       = (const float*)d_in[1];
    const float* seq         = (const float*)d_in[2];
    const float* seq_t       = (const float*)d_in[3];
    const float* seq_e       = (const float*)d_in[4];
    const int*   mask        = (const int*)  d_in[5];
    const float* shared_attn = (const float*)d_in[6];
    const float* fc_w        = (const float*)d_in[7];
    const float* ln_g        = (const float*)d_in[8];
    const float* ln_b        = (const float*)d_in[9];
    const float* w1          = (const float*)d_in[10];
    const float* w2          = (const float*)d_in[11];

    float* out      = (float*)d_out;             // (B, DN)
    float* attn_out = (float*)d_out + B_ * DN_;  // (B, N)

    tgnn_kernel<<<B_, BDIM, 0, stream>>>(src, src_t, seq, seq_t, seq_e, mask,
                                         shared_attn, fc_w, ln_g, ln_b, w1, w2,
                                         out, attn_out);
}